// Round 6
// baseline (112.895 us; speedup 1.0000x reference)
//
#include <hip/hip_runtime.h>
#include <hip/hip_bf16.h>

#define EMB 768
#define HEADS 12
#define DKV 64
#define BATCH 2
#define SEQ 2048
#define NTOK (BATCH*SEQ)   // 4096
#define NROW (24*SEQ)      // 49152 (bh x seq)

typedef float f32x4 __attribute__((ext_vector_type(4)));
typedef unsigned short u16;
typedef u16 u16x8 __attribute__((ext_vector_type(8)));
typedef u16 u16x4 __attribute__((ext_vector_type(4)));
typedef __bf16 bf16x8 __attribute__((ext_vector_type(8)));

__device__ __forceinline__ u16 f2bf(float f) {
  return __builtin_bit_cast(u16, (__bf16)f);
}
__device__ __forceinline__ float bf2f(u16 u) {
  return __builtin_bit_cast(float, (unsigned)u << 16);
}
__device__ __forceinline__ float fexp2(float x) {
#if __has_builtin(__builtin_amdgcn_exp2f)
  return __builtin_amdgcn_exp2f(x);
#else
  return exp2f(x);
#endif
}
__device__ __forceinline__ f32x4 mfma16(u16x8 a, u16x8 b, f32x4 c) {
  return __builtin_amdgcn_mfma_f32_16x16x32_bf16(
      __builtin_bit_cast(bf16x8, a), __builtin_bit_cast(bf16x8, b), c, 0, 0, 0);
}

// ---------------- GEMM core: C[4096,768] = A @ W^T + bias ----------------
// BM=64, BN=128, BK=64; 4 waves (2x2). SINGLE-buffer LDS (24 KB -> 4 blocks/CU,
// VGPR-capped), T14 reg-prefetch: loads for step t+1 issue before compute of t,
// ds_write after barrier. 2 barriers/step. K-loop fully unrolled.
// MODE 0: bf16 head-split [B][H][S][DKV]. MODE 1: fp32 [M][EMB].
// MODE 2: bf16 head-split transposed [B][H][DKV][SEQ].
template<int MODE, bool AF32>
__device__ __forceinline__ void gemm_core(
    const void* __restrict__ Ap, const float* __restrict__ Bm,
    const float* __restrict__ bias, float ascale, float bscale,
    void* __restrict__ outp, u16* __restrict__ At, u16* __restrict__ Bt,
    int m0, int n0)
{
  const int t = threadIdx.x;
  const int w = t >> 6, lane = t & 63, lg = lane >> 4, lr = lane & 15;
  const int wr = w >> 1, wc = w & 1;
  const int tr = t >> 3, tsl = t & 7;   // staging row/slot

  f32x4 acc[2][4] = {};
  f32x4 raf[2][2];
  u16x8 rab[2];
  f32x4 rbf[4][2];

  auto STAGE_LOAD = [&](int kb) {
    #pragma unroll
    for (int q = 0; q < 2; ++q) {
      int row = q*32 + tr;
      if constexpr (AF32) {
        const float* p = (const float*)Ap + (size_t)(m0+row)*EMB + kb + tsl*8;
        raf[q][0] = *reinterpret_cast<const f32x4*>(p);
        raf[q][1] = *reinterpret_cast<const f32x4*>(p + 4);
      } else {
        rab[q] = *reinterpret_cast<const u16x8*>(
            (const u16*)Ap + (size_t)(m0+row)*EMB + kb + tsl*8);
      }
    }
    #pragma unroll
    for (int q = 0; q < 4; ++q) {
      int row = q*32 + tr;
      const float* p = Bm + (size_t)(n0+row)*EMB + kb + tsl*8;
      rbf[q][0] = *reinterpret_cast<const f32x4*>(p);
      rbf[q][1] = *reinterpret_cast<const f32x4*>(p + 4);
    }
  };

  auto STAGE_WRITE = [&]() {
    #pragma unroll
    for (int q = 0; q < 2; ++q) {
      int row = q*32 + tr;
      u16x8 v;
      if constexpr (AF32) {
        #pragma unroll
        for (int j = 0; j < 4; ++j) {
          v[j]   = f2bf(raf[q][0][j] * ascale);
          v[4+j] = f2bf(raf[q][1][j] * ascale);
        }
      } else v = rab[q];
      *reinterpret_cast<u16x8*>(&At[row*64 + ((tsl ^ (row & 7))*8)]) = v;
    }
    #pragma unroll
    for (int q = 0; q < 4; ++q) {
      int row = q*32 + tr;
      u16x8 v;
      #pragma unroll
      for (int j = 0; j < 4; ++j) {
        v[j]   = f2bf(rbf[q][0][j]);
        v[4+j] = f2bf(rbf[q][1][j]);
      }
      *reinterpret_cast<u16x8*>(&Bt[row*64 + ((tsl ^ (row & 7))*8)]) = v;
    }
  };

  auto COMPUTE = [&]() {
    u16x8 af[2][2], bfr[4][2];
    #pragma unroll
    for (int fm = 0; fm < 2; ++fm)
      #pragma unroll
      for (int kk = 0; kk < 2; ++kk) {
        int r = wr*32 + fm*16 + lr;
        int slot = (lg + 4*kk) ^ (r & 7);
        af[fm][kk] = *reinterpret_cast<const u16x8*>(&At[r*64 + slot*8]);
      }
    #pragma unroll
    for (int fn = 0; fn < 4; ++fn)
      #pragma unroll
      for (int kk = 0; kk < 2; ++kk) {
        int r = wc*64 + fn*16 + lr;
        int slot = (lg + 4*kk) ^ (r & 7);
        bfr[fn][kk] = *reinterpret_cast<const u16x8*>(&Bt[r*64 + slot*8]);
      }
    __builtin_amdgcn_s_setprio(1);
    #pragma unroll
    for (int fm = 0; fm < 2; ++fm)
      #pragma unroll
      for (int fn = 0; fn < 4; ++fn)
        #pragma unroll
        for (int kk = 0; kk < 2; ++kk)
          acc[fm][fn] = mfma16(af[fm][kk], bfr[fn][kk], acc[fm][fn]);
    __builtin_amdgcn_s_setprio(0);
  };

  STAGE_LOAD(0);
  STAGE_WRITE();
  __syncthreads();
  const int NSTEP = EMB/64;   // 12
  #pragma unroll
  for (int ts = 0; ts < NSTEP; ++ts) {
    if (ts+1 < NSTEP) STAGE_LOAD((ts+1)*64);   // issue early (T14)
    COMPUTE();
    if (ts+1 < NSTEP) {
      __syncthreads();     // readers of step ts done
      STAGE_WRITE();       // implicit vmcnt wait; loads landed under COMPUTE
      __syncthreads();     // tile ts+1 visible
    }
  }

  // epilogue: C layout col = lane&15, row = (lane>>4)*4 + j  [measured m89]
  #pragma unroll
  for (int fm = 0; fm < 2; ++fm)
    #pragma unroll
    for (int fn = 0; fn < 4; ++fn) {
      const int mb = m0 + wr*32 + fm*16 + lg*4;
      const int e  = n0 + wc*64 + fn*16 + lr;
      if constexpr (MODE == 2) {
        int bb = mb >> 11, sb = mb & 2047, h = e >> 6, d = e & 63;
        u16x4 o4;
        #pragma unroll
        for (int j = 0; j < 4; ++j) o4[j] = f2bf(acc[fm][fn][j] + bias[e]*bscale);
        *reinterpret_cast<u16x4*>(
            reinterpret_cast<u16*>(outp) + (((size_t)(bb*HEADS+h))*DKV + d)*SEQ + sb) = o4;
      } else {
        #pragma unroll
        for (int j = 0; j < 4; ++j) {
          int m = mb + j;
          float val = acc[fm][fn][j] + bias[e]*bscale;
          if constexpr (MODE == 0) {
            int bb = m >> 11, s = m & 2047, h = e >> 6, d = e & 63;
            reinterpret_cast<u16*>(outp)[(((size_t)(bb*HEADS+h))*SEQ + s)*DKV + d] = f2bf(val);
          } else {
            reinterpret_cast<float*>(outp)[(size_t)m*EMB + e] = val;
          }
        }
      }
    }
}

// fused Q/K/V projections: blockIdx.z selects which
__global__ __launch_bounds__(256) void qkv_k(
    const float* __restrict__ Aq, const float* __restrict__ Ak, const float* __restrict__ Av,
    const float* __restrict__ Wq, const float* __restrict__ Wk, const float* __restrict__ Wv,
    const float* __restrict__ bq, const float* __restrict__ bk, const float* __restrict__ bv,
    u16* __restrict__ Qh, u16* __restrict__ Kh, u16* __restrict__ Vh, float csc)
{
  __shared__ __align__(16) u16 At[64*64];
  __shared__ __align__(16) u16 Bt[128*64];
  const int m0 = blockIdx.x*64, n0 = blockIdx.y*128;
  const int z = blockIdx.z;
  if (z == 0)
    gemm_core<0,true>(Aq, Wq, bq, csc, csc, Qh, At, Bt, m0, n0);
  else if (z == 1)
    gemm_core<0,true>(Ak, Wk, bk, 1.f, 1.f, Kh, At, Bt, m0, n0);
  else
    gemm_core<2,true>(Av, Wv, bv, 1.f, 1.f, Vh, At, Bt, m0, n0);
}

// output projection
__global__ __launch_bounds__(256) void gemm_out_k(
    const u16* __restrict__ A, const float* __restrict__ Bm,
    const float* __restrict__ bias, float* __restrict__ outp)
{
  __shared__ __align__(16) u16 At[64*64];
  __shared__ __align__(16) u16 Bt[128*64];
  gemm_core<1,false>(A, Bm, bias, 1.f, 1.f, outp, At, Bt, blockIdx.x*64, blockIdx.y*128);
}

// ---------------- flash attention, split-K x2 (flash-decoding) ----------------
// blockIdx.z = key-half; each block does 16 K-tiles, writes UNNORMALIZED partial
// acc (bf16) + (m,l) (f32). Single-buffered K/V (24 KB LDS -> 6 blocks/CU),
// T14 early reg-loads, 2 barriers/tile. Swapped QK^T, per-lane base-2 softmax,
// defer-rescale (T13), setprio (T5).
__global__ __launch_bounds__(256) void flash_attn_k(
    const u16* __restrict__ Q, const u16* __restrict__ K, const u16* __restrict__ VT,
    u16* __restrict__ Pacc, float* __restrict__ Pml)
{
  __shared__ __align__(16) u16 Kt[64*64];       // [key][d] swizzled
  __shared__ __align__(16) u16 Vt[64*64];       // [d][key] swizzled
  __shared__ __align__(16) u16 Pt[4][16*64];    // per-wave [q][k] swizzled

  const int t = threadIdx.x;
  const int w = t >> 6, lane = t & 63, lg = lane >> 4, lr = lane & 15;
  const int tr = t >> 3, tsl = t & 7;
  const int qb = blockIdx.x;       // 0..31
  const int bh = blockIdx.y;       // 0..23
  const int z  = blockIdx.z;       // 0..1 key half
  const u16* Qb = Q  + (size_t)bh*SEQ*DKV;
  const u16* Kb = K  + (size_t)bh*SEQ*DKV;
  const u16* Vb = VT + (size_t)bh*DKV*SEQ;

  const int qrow = qb*64 + w*16 + lr;
  u16x8 qf[2];
  qf[0] = *reinterpret_cast<const u16x8*>(Qb + (size_t)qrow*DKV + lg*8);
  qf[1] = *reinterpret_cast<const u16x8*>(Qb + (size_t)qrow*DKV + 32 + lg*8);

  f32x4 acc[4] = {};   // O^T: acc[fc][j] -> d = fc*16+lg*4+j, q = lr
  float mrun = -1e30f, lrun = 0.f;

  u16x8 ks[2], vs[2];
  auto LOADKV = [&](int kt0) {
    #pragma unroll
    for (int q = 0; q < 2; ++q) {
      int row = q*32 + tr;
      ks[q] = *reinterpret_cast<const u16x8*>(Kb + (size_t)(kt0+row)*DKV + tsl*8);
    }
    #pragma unroll
    for (int q = 0; q < 2; ++q) {
      int d = q*32 + tr;
      vs[q] = *reinterpret_cast<const u16x8*>(Vb + (size_t)d*SEQ + kt0 + tsl*8);
    }
  };
  auto WRITEKV = [&]() {
    #pragma unroll
    for (int q = 0; q < 2; ++q) {
      int row = q*32 + tr;
      *reinterpret_cast<u16x8*>(&Kt[row*64 + ((tsl ^ (row & 7))*8)]) = ks[q];
    }
    #pragma unroll
    for (int q = 0; q < 2; ++q) {
      int d = q*32 + tr;
      *reinterpret_cast<u16x8*>(&Vt[d*64 + ((tsl ^ (d & 7))*8)]) = vs[q];
    }
  };

  const int NT2 = SEQ/64/2;            // 16 tiles per split
  const int ktbase = z*NT2;            // tile offset
  char* Pw = reinterpret_cast<char*>(&Pt[w][0]);

  LOADKV(ktbase*64);
  WRITEKV();
  __syncthreads();

  for (int kt = 0; kt < NT2; ++kt) {
    if (kt+1 < NT2) LOADKV((ktbase+kt+1)*64);   // issue early (T14)

    // S^T[key][q] = mfma(K, Q)
    f32x4 s[4];
    __builtin_amdgcn_s_setprio(1);
    #pragma unroll
    for (int fc = 0; fc < 4; ++fc) {
      f32x4 zz = {};
      #pragma unroll
      for (int kk = 0; kk < 2; ++kk) {
        int r = fc*16 + lr;
        int slot = (lg + 4*kk) ^ (r & 7);
        u16x8 kf = *reinterpret_cast<const u16x8*>(&Kt[r*64 + slot*8]);
        zz = mfma16(kf, qf[kk], zz);
      }
      s[fc] = zz;
    }
    __builtin_amdgcn_s_setprio(0);

    // per-lane online softmax (lane owns q=lr; 16 of 64 keys local)
    float a0 = fmaxf(fmaxf(s[0][0], s[0][1]), s[0][2]);
    float a1 = fmaxf(fmaxf(s[0][3], s[1][0]), s[1][1]);
    float a2 = fmaxf(fmaxf(s[1][2], s[1][3]), s[2][0]);
    float a3 = fmaxf(fmaxf(s[2][1], s[2][2]), s[2][3]);
    float a4 = fmaxf(fmaxf(s[3][0], s[3][1]), s[3][2]);
    float pmax = fmaxf(fmaxf(fmaxf(a0, a1), a2),
                       fmaxf(fmaxf(a3, a4), s[3][3]));
    pmax = fmaxf(pmax, __shfl_xor(pmax, 16));
    pmax = fmaxf(pmax, __shfl_xor(pmax, 32));

    if (!__all(pmax <= mrun + 8.f)) {   // defer-rescale (T13)
      float mnew = fmaxf(mrun, pmax);
      float corr = fexp2(mrun - mnew);
      mrun = mnew; lrun *= corr;
      #pragma unroll
      for (int fc = 0; fc < 4; ++fc)
        #pragma unroll
        for (int j = 0; j < 4; ++j)
          acc[fc][j] *= corr;
    }

    float p[4][4], rs[4];
    #pragma unroll
    for (int fc = 0; fc < 4; ++fc) {
      #pragma unroll
      for (int j = 0; j < 4; ++j) p[fc][j] = fexp2(s[fc][j] - mrun);
      rs[fc] = (p[fc][0] + p[fc][1]) + (p[fc][2] + p[fc][3]);
    }
    float rsum = (rs[0] + rs[1]) + (rs[2] + rs[3]);
    rsum += __shfl_xor(rsum, 16);
    rsum += __shfl_xor(rsum, 32);
    lrun += rsum;

    // P -> bf16 into per-wave swizzled tile
    #pragma unroll
    for (int fc = 0; fc < 4; ++fc) {
      u16x4 q4;
      #pragma unroll
      for (int j = 0; j < 4; ++j) q4[j] = f2bf(p[fc][j]);
      *reinterpret_cast<u16x4*>(Pw + lr*128 + (((fc*4 + lg) ^ ((lr & 7) << 1))*8)) = q4;
    }
    asm volatile("s_waitcnt lgkmcnt(0)" ::: "memory");
    __builtin_amdgcn_sched_barrier(0);

    // PV: O^T[d][q] += V^T[d][k] * P^T[k][q]
    __builtin_amdgcn_s_setprio(1);
    #pragma unroll
    for (int kk = 0; kk < 2; ++kk) {
      u16x8 pf = *reinterpret_cast<const u16x8*>(
          Pw + lr*128 + (((kk*8 + lg*2) ^ ((lr & 7) << 1))*8));
      #pragma unroll
      for (int fc = 0; fc < 4; ++fc) {
        int rv = fc*16 + lr;
        int slotv = (lg + 4*kk) ^ (rv & 7);
        u16x8 vf = *reinterpret_cast<const u16x8*>(&Vt[rv*64 + slotv*8]);
        acc[fc] = mfma16(vf, pf, acc[fc]);
      }
    }
    __builtin_amdgcn_s_setprio(0);

    if (kt+1 < NT2) {
      __syncthreads();   // readers of tile kt done
      WRITEKV();         // implicit vmcnt wait; loads landed under compute
      __syncthreads();   // tile kt+1 visible
    }
  }

  // write partials: unnormalized acc (bf16) + (m,l) f32
  const int prow = bh*SEQ + qrow;          // 0..NROW-1
  u16* pa = Pacc + ((size_t)(z*NROW + prow))*DKV;
  #pragma unroll
  for (int fc = 0; fc < 4; ++fc) {
    u16x4 o4;
    #pragma unroll
    for (int j = 0; j < 4; ++j) o4[j] = f2bf(acc[fc][j]);
    *reinterpret_cast<u16x4*>(pa + fc*16 + lg*4) = o4;
  }
  if (lane < 16) {
    float2 ml; ml.x = mrun; ml.y = lrun;
    *reinterpret_cast<float2*>(Pml + (size_t)(z*NROW + prow)*2) = ml;
  }
}

// ---------------- merge split-K partials -> Xb[b][s][h*64+d] bf16 ----------------
__global__ __launch_bounds__(256) void merge_k(
    const u16* __restrict__ Pacc, const float* __restrict__ Pml,
    u16* __restrict__ Xb)
{
  int row = blockIdx.x*256 + threadIdx.x;   // 0..NROW-1
  int bh = row >> 11, s = row & 2047;
  int b = bh / HEADS, h = bh % HEADS;
  float2 ml1 = *reinterpret_cast<const float2*>(Pml + (size_t)row*2);
  float2 ml2 = *reinterpret_cast<const float2*>(Pml + (size_t)(NROW + row)*2);
  float g  = fmaxf(ml1.x, ml2.x);
  float w1 = fexp2(ml1.x - g), w2 = fexp2(ml2.x - g);
  float inv = 1.0f / (ml1.y*w1 + ml2.y*w2);
  w1 *= inv; w2 *= inv;
  const u16* a1 = Pacc + (size_t)row*DKV;
  const u16* a2 = Pacc + (size_t)(NROW + row)*DKV;
  u16* o = Xb + ((size_t)(b*SEQ + s))*EMB + h*64;
  #pragma unroll
  for (int q = 0; q < 8; ++q) {
    u16x8 v1 = *reinterpret_cast<const u16x8*>(a1 + q*8);
    u16x8 v2 = *reinterpret_cast<const u16x8*>(a2 + q*8);
    u16x8 ov;
    #pragma unroll
    for (int j = 0; j < 8; ++j)
      ov[j] = f2bf(bf2f(v1[j])*w1 + bf2f(v2[j])*w2);
    *reinterpret_cast<u16x8*>(o + q*8) = ov;
  }
}

// ---------------- launcher: 4 kernels ----------------
extern "C" void kernel_launch(void* const* d_in, const int* in_sizes, int n_in,
                              void* d_out, int out_size, void* d_ws, size_t ws_size,
                              hipStream_t stream) {
  const float* xq_f = (const float*)d_in[0];
  const float* xk_f = (const float*)d_in[1];
  const float* xv_f = (const float*)d_in[2];
  const float* Wq = (const float*)d_in[3];
  const float* bq = (const float*)d_in[4];
  const float* Wk = (const float*)d_in[5];
  const float* bk = (const float*)d_in[6];
  const float* Wv = (const float*)d_in[7];
  const float* bv = (const float*)d_in[8];
  const float* Wo = (const float*)d_in[9];
  const float* bo = (const float*)d_in[10];

  u16* Qh = (u16*)d_ws;                          // [B][H][S][DKV] bf16   6.3 MB
  u16* Kh = Qh + (size_t)NTOK*EMB;               //                       6.3 MB
  u16* Vh = Kh + (size_t)NTOK*EMB;               // [B][H][DKV][SEQ]      6.3 MB
  u16* Xb = Vh + (size_t)NTOK*EMB;               // attn out bf16         6.3 MB
  u16* Pacc = Xb + (size_t)NTOK*EMB;             // [2][NROW][64] bf16   12.6 MB
  float* Pml = (float*)(Pacc + (size_t)2*NROW*DKV); // [2][NROW][2] f32   0.8 MB
                                                  // total ~38.5 MB

  const float csc = 0.125f * 1.4426950408889634f;  // score scale -> Q proj

  qkv_k<<<dim3(NTOK/64, EMB/128, 3), dim3(256), 0, stream>>>(
      xq_f, xk_f, xv_f, Wq, Wk, Wv, bq, bk, bv, Qh, Kh, Vh, csc);

  flash_attn_k<<<dim3(SEQ/64, BATCH*HEADS, 2), dim3(256), 0, stream>>>(
      Qh, Kh, Vh, Pacc, Pml);

  merge_k<<<dim3(NROW/256), dim3(256), 0, stream>>>(Pacc, Pml, Xb);

  gemm_out_k<<<dim3(NTOK/64, EMB/128), dim3(256), 0, stream>>>(Xb, Wo, bo, (float*)d_out);
}

// Round 7
// 101.003 us; speedup vs baseline: 1.1177x; 1.1177x over previous
//
#include <hip/hip_runtime.h>
#include <hip/hip_bf16.h>

#define EMB 768
#define HEADS 12
#define DKV 64
#define BATCH 2
#define SEQ 2048
#define NTOK (BATCH*SEQ)   // 4096

typedef float f32x4 __attribute__((ext_vector_type(4)));
typedef unsigned short u16;
typedef u16 u16x8 __attribute__((ext_vector_type(8)));
typedef u16 u16x4 __attribute__((ext_vector_type(4)));
typedef __bf16 bf16x8 __attribute__((ext_vector_type(8)));

__device__ __forceinline__ u16 f2bf(float f) {
  return __builtin_bit_cast(u16, (__bf16)f);
}
__device__ __forceinline__ float fexp2(float x) {
#if __has_builtin(__builtin_amdgcn_exp2f)
  return __builtin_amdgcn_exp2f(x);
#else
  return exp2f(x);
#endif
}
__device__ __forceinline__ f32x4 mfma16(u16x8 a, u16x8 b, f32x4 c) {
  return __builtin_amdgcn_mfma_f32_16x16x32_bf16(
      __builtin_bit_cast(bf16x8, a), __builtin_bit_cast(bf16x8, b), c, 0, 0, 0);
}

// ---------------- GEMM core: C[4096,768] = A @ W^T + bias ----------------
// BM=64, BN=128, BK=64; 4 waves (2x2). AF32: fp32 A cast in-register during staging.
// Double-buffered LDS, ONE barrier per K-step, K-loop fully unrolled (buffer index
// compile-time -> all LDS addresses fold to base+imm). T14 early loads.
// MODE 0: bf16 head-split [B][H][S][DKV]. MODE 1: fp32 [M][EMB].
// MODE 2: bf16 head-split transposed [B][H][DKV][SEQ].
template<int MODE, bool AF32>
__device__ __forceinline__ void gemm_core(
    const void* __restrict__ Ap, const float* __restrict__ Bm,
    const float* __restrict__ bias, float ascale, float bscale,
    void* __restrict__ outp, u16* __restrict__ At, u16* __restrict__ Bt,
    int m0, int n0)
{
  const int t = threadIdx.x;
  const int w = t >> 6, lane = t & 63, lg = lane >> 4, lr = lane & 15;
  const int wr = w >> 1, wc = w & 1;
  const int tr = t >> 3, tsl = t & 7;   // staging row/slot

  f32x4 acc[2][4] = {};
  f32x4 raf[2][2];
  u16x8 rab[2];
  f32x4 rbf[4][2];

  auto STAGE_LOAD = [&](int kb) {
    #pragma unroll
    for (int q = 0; q < 2; ++q) {
      int row = q*32 + tr;
      if constexpr (AF32) {
        const float* p = (const float*)Ap + (size_t)(m0+row)*EMB + kb + tsl*8;
        raf[q][0] = *reinterpret_cast<const f32x4*>(p);
        raf[q][1] = *reinterpret_cast<const f32x4*>(p + 4);
      } else {
        rab[q] = *reinterpret_cast<const u16x8*>(
            (const u16*)Ap + (size_t)(m0+row)*EMB + kb + tsl*8);
      }
    }
    #pragma unroll
    for (int q = 0; q < 4; ++q) {
      int row = q*32 + tr;
      const float* p = Bm + (size_t)(n0+row)*EMB + kb + tsl*8;
      rbf[q][0] = *reinterpret_cast<const f32x4*>(p);
      rbf[q][1] = *reinterpret_cast<const f32x4*>(p + 4);
    }
  };

  auto STAGE_WRITE = [&](int bi) {
    #pragma unroll
    for (int q = 0; q < 2; ++q) {
      int row = q*32 + tr;
      u16x8 v;
      if constexpr (AF32) {
        #pragma unroll
        for (int j = 0; j < 4; ++j) {
          v[j]   = f2bf(raf[q][0][j] * ascale);
          v[4+j] = f2bf(raf[q][1][j] * ascale);
        }
      } else v = rab[q];
      *reinterpret_cast<u16x8*>(&At[bi*4096 + row*64 + ((tsl ^ (row & 7))*8)]) = v;
    }
    #pragma unroll
    for (int q = 0; q < 4; ++q) {
      int row = q*32 + tr;
      u16x8 v;
      #pragma unroll
      for (int j = 0; j < 4; ++j) {
        v[j]   = f2bf(rbf[q][0][j]);
        v[4+j] = f2bf(rbf[q][1][j]);
      }
      *reinterpret_cast<u16x8*>(&Bt[bi*8192 + row*64 + ((tsl ^ (row & 7))*8)]) = v;
    }
  };

  auto COMPUTE = [&](int bi) {
    u16x8 af[2][2], bfr[4][2];
    #pragma unroll
    for (int fm = 0; fm < 2; ++fm)
      #pragma unroll
      for (int kk = 0; kk < 2; ++kk) {
        int r = wr*32 + fm*16 + lr;
        int slot = (lg + 4*kk) ^ (r & 7);
        af[fm][kk] = *reinterpret_cast<const u16x8*>(&At[bi*4096 + r*64 + slot*8]);
      }
    #pragma unroll
    for (int fn = 0; fn < 4; ++fn)
      #pragma unroll
      for (int kk = 0; kk < 2; ++kk) {
        int r = wc*64 + fn*16 + lr;
        int slot = (lg + 4*kk) ^ (r & 7);
        bfr[fn][kk] = *reinterpret_cast<const u16x8*>(&Bt[bi*8192 + r*64 + slot*8]);
      }
    __builtin_amdgcn_s_setprio(1);
    #pragma unroll
    for (int fm = 0; fm < 2; ++fm)
      #pragma unroll
      for (int fn = 0; fn < 4; ++fn)
        #pragma unroll
        for (int kk = 0; kk < 2; ++kk)
          acc[fm][fn] = mfma16(af[fm][kk], bfr[fn][kk], acc[fm][fn]);
    __builtin_amdgcn_s_setprio(0);
  };

  STAGE_LOAD(0);
  STAGE_WRITE(0);
  __syncthreads();
  const int NSTEP = EMB/64;   // 12
  #pragma unroll
  for (int ts = 0; ts < NSTEP-1; ++ts) {
    STAGE_LOAD((ts+1)*64);
    COMPUTE(ts & 1);
    STAGE_WRITE((ts & 1) ^ 1);
    __syncthreads();
  }
  COMPUTE((NSTEP-1) & 1);

  // epilogue: C layout col = lane&15, row = (lane>>4)*4 + j  [measured m89]
  #pragma unroll
  for (int fm = 0; fm < 2; ++fm)
    #pragma unroll
    for (int fn = 0; fn < 4; ++fn) {
      const int mb = m0 + wr*32 + fm*16 + lg*4;
      const int e  = n0 + wc*64 + fn*16 + lr;
      if constexpr (MODE == 2) {
        int bb = mb >> 11, sb = mb & 2047, h = e >> 6, d = e & 63;
        u16x4 o4;
        #pragma unroll
        for (int j = 0; j < 4; ++j) o4[j] = f2bf(acc[fm][fn][j] + bias[e]*bscale);
        *reinterpret_cast<u16x4*>(
            reinterpret_cast<u16*>(outp) + (((size_t)(bb*HEADS+h))*DKV + d)*SEQ + sb) = o4;
      } else {
        #pragma unroll
        for (int j = 0; j < 4; ++j) {
          int m = mb + j;
          float val = acc[fm][fn][j] + bias[e]*bscale;
          if constexpr (MODE == 0) {
            int bb = m >> 11, s = m & 2047, h = e >> 6, d = e & 63;
            reinterpret_cast<u16*>(outp)[(((size_t)(bb*HEADS+h))*SEQ + s)*DKV + d] = f2bf(val);
          } else {
            reinterpret_cast<float*>(outp)[(size_t)m*EMB + e] = val;
          }
        }
      }
    }
}

// fused Q/K/V projections: blockIdx.z selects which
__global__ __launch_bounds__(256) void qkv_k(
    const float* __restrict__ Aq, const float* __restrict__ Ak, const float* __restrict__ Av,
    const float* __restrict__ Wq, const float* __restrict__ Wk, const float* __restrict__ Wv,
    const float* __restrict__ bq, const float* __restrict__ bk, const float* __restrict__ bv,
    u16* __restrict__ Qh, u16* __restrict__ Kh, u16* __restrict__ Vh, float csc)
{
  __shared__ __align__(16) u16 At[2*64*64];
  __shared__ __align__(16) u16 Bt[2*128*64];
  const int m0 = blockIdx.x*64, n0 = blockIdx.y*128;
  const int z = blockIdx.z;
  if (z == 0)
    gemm_core<0,true>(Aq, Wq, bq, csc, csc, Qh, At, Bt, m0, n0);
  else if (z == 1)
    gemm_core<0,true>(Ak, Wk, bk, 1.f, 1.f, Kh, At, Bt, m0, n0);
  else
    gemm_core<2,true>(Av, Wv, bv, 1.f, 1.f, Vh, At, Bt, m0, n0);
}

// output projection
__global__ __launch_bounds__(256) void gemm_out_k(
    const u16* __restrict__ A, const float* __restrict__ Bm,
    const float* __restrict__ bias, float* __restrict__ outp)
{
  __shared__ __align__(16) u16 At[2*64*64];
  __shared__ __align__(16) u16 Bt[2*128*64];
  gemm_core<1,false>(A, Bm, bias, 1.f, 1.f, outp, At, Bt, blockIdx.x*64, blockIdx.y*128);
}

// ---------------- flash attention (swapped-QK^T, per-lane softmax) ----------------
// Round-5 double-buffered structure + serial-chain diet:
//  * per-lane PARTIAL lrun (the 4 lg-lanes of a q-row each keep their own sum,
//    rescaled by the uniform corr) -> per-tile sum shuffles removed; one
//    cross-lane reduce in the epilogue.
//  * defer-max gates the cross-lane max-reduce itself: lane-local fmax tree
//    always; full 2-shuffle max + rescale only when __any(local > mrun+8)
//    (uniform scalar branch). p <= 2^8 — same THR=8 envelope as before.
__global__ __launch_bounds__(256) void flash_attn_k(
    const u16* __restrict__ Q, const u16* __restrict__ K, const u16* __restrict__ VT,
    u16* __restrict__ av)
{
  __shared__ __align__(16) u16 Kt[2][64*64];     // [key][d] swizzled
  __shared__ __align__(16) u16 Vt[2][64*64];     // [d][key] swizzled
  __shared__ __align__(16) u16 Pt[4][16*64];     // per-wave [q][k] swizzled

  const int t = threadIdx.x;
  const int w = t >> 6, lane = t & 63, lg = lane >> 4, lr = lane & 15;
  const int tr = t >> 3, tsl = t & 7;
  const int qb = blockIdx.x;       // 0..31
  const int bh = blockIdx.y;       // 0..23
  const u16* Qb = Q  + (size_t)bh*SEQ*DKV;
  const u16* Kb = K  + (size_t)bh*SEQ*DKV;
  const u16* Vb = VT + (size_t)bh*DKV*SEQ;

  const int qrow = qb*64 + w*16 + lr;
  u16x8 qf[2];
  qf[0] = *reinterpret_cast<const u16x8*>(Qb + (size_t)qrow*DKV + lg*8);
  qf[1] = *reinterpret_cast<const u16x8*>(Qb + (size_t)qrow*DKV + 32 + lg*8);

  f32x4 acc[4] = {};   // O^T: acc[fc][j] -> d = fc*16+lg*4+j, q = lr
  float mrun = -1e30f, lrun = 0.f;   // lrun is a per-lane PARTIAL (16 keys/tile)

  u16x8 ks[2], vs[2];
  auto LOADKV = [&](int kt0) {
    #pragma unroll
    for (int q = 0; q < 2; ++q) {
      int row = q*32 + tr;
      ks[q] = *reinterpret_cast<const u16x8*>(Kb + (size_t)(kt0+row)*DKV + tsl*8);
    }
    #pragma unroll
    for (int q = 0; q < 2; ++q) {
      int d = q*32 + tr;
      vs[q] = *reinterpret_cast<const u16x8*>(Vb + (size_t)d*SEQ + kt0 + tsl*8);
    }
  };

  const int NT = SEQ/64;   // 32
  LOADKV(0);
  {
    #pragma unroll
    for (int q = 0; q < 2; ++q) {
      int row = q*32 + tr;
      *reinterpret_cast<u16x8*>(&Kt[0][row*64 + ((tsl ^ (row & 7))*8)]) = ks[q];
    }
    #pragma unroll
    for (int q = 0; q < 2; ++q) {
      int d = q*32 + tr;
      *reinterpret_cast<u16x8*>(&Vt[0][d*64 + ((tsl ^ (d & 7))*8)]) = vs[q];
    }
  }
  __syncthreads();

  char* Pw = reinterpret_cast<char*>(&Pt[w][0]);

#define TILE(bi, kt)                                                          \
  do {                                                                        \
    if ((kt)+1 < NT) LOADKV(((kt)+1)*64);                                     \
    f32x4 s[4];                                                               \
    __builtin_amdgcn_s_setprio(1);                                            \
    _Pragma("unroll")                                                         \
    for (int fc = 0; fc < 4; ++fc) {                                          \
      f32x4 z = {};                                                           \
      _Pragma("unroll")                                                       \
      for (int kk = 0; kk < 2; ++kk) {                                        \
        int r = fc*16 + lr;                                                   \
        int slot = (lg + 4*kk) ^ (r & 7);                                     \
        u16x8 kf = *reinterpret_cast<const u16x8*>(&Kt[bi][r*64 + slot*8]);   \
        z = mfma16(kf, qf[kk], z);                                            \
      }                                                                       \
      s[fc] = z;                                                              \
    }                                                                         \
    __builtin_amdgcn_s_setprio(0);                                            \
    float a0 = fmaxf(fmaxf(s[0][0], s[0][1]), s[0][2]);                       \
    float a1 = fmaxf(fmaxf(s[0][3], s[1][0]), s[1][1]);                       \
    float a2 = fmaxf(fmaxf(s[1][2], s[1][3]), s[2][0]);                       \
    float a3 = fmaxf(fmaxf(s[2][1], s[2][2]), s[2][3]);                       \
    float a4 = fmaxf(fmaxf(s[3][0], s[3][1]), s[3][2]);                       \
    float pmax = fmaxf(fmaxf(fmaxf(a0, a1), a2),                              \
                       fmaxf(fmaxf(a3, a4), s[3][3]));                        \
    if (__any(pmax > mrun + 8.f)) {   /* rare: full reduce + rescale */       \
      float pm = fmaxf(pmax, __shfl_xor(pmax, 16));                           \
      pm = fmaxf(pm, __shfl_xor(pm, 32));                                     \
      float mnew = fmaxf(mrun, pm);                                           \
      float corr = fexp2(mrun - mnew);                                        \
      mrun = mnew; lrun *= corr;                                              \
      _Pragma("unroll")                                                       \
      for (int fc = 0; fc < 4; ++fc)                                          \
        _Pragma("unroll")                                                     \
        for (int j = 0; j < 4; ++j)                                           \
          acc[fc][j] *= corr;                                                 \
    }                                                                         \
    float p[4][4], rs[4];                                                     \
    _Pragma("unroll")                                                         \
    for (int fc = 0; fc < 4; ++fc) {                                          \
      _Pragma("unroll")                                                       \
      for (int j = 0; j < 4; ++j) p[fc][j] = fexp2(s[fc][j] - mrun);          \
      rs[fc] = (p[fc][0] + p[fc][1]) + (p[fc][2] + p[fc][3]);                 \
    }                                                                         \
    lrun += (rs[0] + rs[1]) + (rs[2] + rs[3]);   /* partial: no shuffles */   \
    _Pragma("unroll")                                                         \
    for (int fc = 0; fc < 4; ++fc) {                                          \
      u16x4 q4;                                                               \
      _Pragma("unroll")                                                       \
      for (int j = 0; j < 4; ++j) q4[j] = f2bf(p[fc][j]);                     \
      *reinterpret_cast<u16x4*>(                                              \
          Pw + lr*128 + (((fc*4 + lg) ^ ((lr & 7) << 1))*8)) = q4;            \
    }                                                                         \
    asm volatile("s_waitcnt lgkmcnt(0)" ::: "memory");                        \
    __builtin_amdgcn_sched_barrier(0);                                        \
    __builtin_amdgcn_s_setprio(1);                                            \
    _Pragma("unroll")                                                         \
    for (int kk = 0; kk < 2; ++kk) {                                          \
      u16x8 pf = *reinterpret_cast<const u16x8*>(                             \
          Pw + lr*128 + (((kk*8 + lg*2) ^ ((lr & 7) << 1))*8));               \
      _Pragma("unroll")                                                       \
      for (int fc = 0; fc < 4; ++fc) {                                        \
        int rv = fc*16 + lr;                                                  \
        int slotv = (lg + 4*kk) ^ (rv & 7);                                   \
        u16x8 vf = *reinterpret_cast<const u16x8*>(&Vt[bi][rv*64 + slotv*8]); \
        acc[fc] = mfma16(vf, pf, acc[fc]);                                    \
      }                                                                       \
    }                                                                         \
    __builtin_amdgcn_s_setprio(0);                                            \
    if ((kt)+1 < NT) {                                                        \
      _Pragma("unroll")                                                       \
      for (int q = 0; q < 2; ++q) {                                           \
        int row = q*32 + tr;                                                  \
        *reinterpret_cast<u16x8*>(                                            \
            &Kt[(bi)^1][row*64 + ((tsl ^ (row & 7))*8)]) = ks[q];             \
      }                                                                       \
      _Pragma("unroll")                                                       \
      for (int q = 0; q < 2; ++q) {                                           \
        int d = q*32 + tr;                                                    \
        *reinterpret_cast<u16x8*>(                                            \
            &Vt[(bi)^1][d*64 + ((tsl ^ (d & 7))*8)]) = vs[q];                 \
      }                                                                       \
    }                                                                         \
    __syncthreads();                                                          \
  } while (0)

  for (int kt = 0; kt < NT; kt += 2) {
    TILE(0, kt);
    TILE(1, kt+1);
  }
#undef TILE

  // epilogue: combine partial l across the 4 lg-lanes of each q-row (once),
  // then normalize. lane owns q=qrow; d contiguous -> 8B stores.
  float lt = lrun;
  lt += __shfl_xor(lt, 16);
  lt += __shfl_xor(lt, 32);
  const float inv = 1.0f / lt;

  const int b = bh / HEADS, h = bh % HEADS;
  #pragma unroll
  for (int fc = 0; fc < 4; ++fc) {
    u16x4 o4;
    #pragma unroll
    for (int j = 0; j < 4; ++j) o4[j] = f2bf(acc[fc][j] * inv);
    *reinterpret_cast<u16x4*>(
        av + ((size_t)(b*SEQ + qrow))*EMB + h*64 + fc*16 + lg*4) = o4;
  }
}

// ---------------- launcher: 3 kernels ----------------
extern "C" void kernel_launch(void* const* d_in, const int* in_sizes, int n_in,
                              void* d_out, int out_size, void* d_ws, size_t ws_size,
                              hipStream_t stream) {
  const float* xq_f = (const float*)d_in[0];
  const float* xk_f = (const float*)d_in[1];
  const float* xv_f = (const float*)d_in[2];
  const float* Wq = (const float*)d_in[3];
  const float* bq = (const float*)d_in[4];
  const float* Wk = (const float*)d_in[5];
  const float* bk = (const float*)d_in[6];
  const float* Wv = (const float*)d_in[7];
  const float* bv = (const float*)d_in[8];
  const float* Wo = (const float*)d_in[9];
  const float* bo = (const float*)d_in[10];

  u16* Qh = (u16*)d_ws;                       // [B][H][S][DKV] bf16
  u16* Kh = Qh + (size_t)NTOK*EMB;
  u16* Vh = Kh + (size_t)NTOK*EMB;            // [B][H][DKV][SEQ] bf16 (V^T)
  u16* Xb = Vh + (size_t)NTOK*EMB;            // attention output bf16

  const float csc = 0.125f * 1.4426950408889634f;  // score scale, folded into Q proj

  qkv_k<<<dim3(NTOK/64, EMB/128, 3), dim3(256), 0, stream>>>(
      xq_f, xk_f, xv_f, Wq, Wk, Wv, bq, bk, bv, Qh, Kh, Vh, csc);

  flash_attn_k<<<dim3(SEQ/64, BATCH*HEADS), dim3(256), 0, stream>>>(Qh, Kh, Vh, Xb);

  gemm_out_k<<<dim3(NTOK/64, EMB/128), dim3(256), 0, stream>>>(Xb, Wo, bo, (float*)d_out);
}